// Round 3
// baseline (159.076 us; speedup 1.0000x reference)
//
#include <hip/hip_runtime.h>

#define B 256
#define EPSV 1e-5f

// ---------- output offsets (f32 elements) ----------
#define OFF_ASSIGN 0
#define OFF_LOSS   256
#define OFF_ACT4   257
#define OFF_L1     2817
#define OFF_L2     12847873
#define OFF_L3     14486273

__device__ inline void wave_reduce2(float& s, float& q) {
#pragma unroll
    for (int o = 32; o > 0; o >>= 1) {
        s += __shfl_down(s, o, 64);
        q += __shfl_down(q, o, 64);
    }
}

// conv1 pass 1: [B,3,32,32] -> per-(b,c) sum/sumsq partials only (no activation store)
__global__ void conv1_stats_kernel(const float* __restrict__ inp, const float* __restrict__ w,
                                   const float* __restrict__ bias, float* __restrict__ part) {
    int bc = blockIdx.x; int b = bc / 6, c = bc % 6;
    int tid = threadIdx.x;
    __shared__ float ws[75];
    __shared__ float rs[4], rq[4];
    if (tid < 75) ws[tid] = w[c * 75 + tid];
    __syncthreads();
    const float* ip = inp + b * 3072;
    float bs = bias[c];
    float s = 0.f, sq = 0.f;
    for (int hw = tid; hw < 784; hw += 256) {
        int oh = hw / 28, ow = hw % 28;
        float acc = bs;
#pragma unroll
        for (int ic = 0; ic < 3; ++ic) {
            const float* ipc = ip + ic * 1024 + oh * 32 + ow;
            const float* wc = ws + ic * 25;
#pragma unroll
            for (int kh = 0; kh < 5; ++kh)
#pragma unroll
                for (int kw = 0; kw < 5; ++kw)
                    acc += ipc[kh * 32 + kw] * wc[kh * 5 + kw];
        }
        s += acc; sq += acc * acc;
    }
    wave_reduce2(s, sq);
    if ((tid & 63) == 0) { rs[tid >> 6] = s; rq[tid >> 6] = sq; }
    __syncthreads();
    if (tid == 0) {
        part[bc * 2]     = rs[0] + rs[1] + rs[2] + rs[3];
        part[bc * 2 + 1] = rq[0] + rq[1] + rq[2] + rq[3];
    }
}

// per-channel stats from B partials; grid = C blocks, 256 thr (one per b)
__global__ void stats_kernel(const float* __restrict__ part, float* __restrict__ stats,
                             int C, float invN) {
    int c = blockIdx.x, tid = threadIdx.x;
    float s = part[(tid * C + c) * 2];
    float q = part[(tid * C + c) * 2 + 1];
    wave_reduce2(s, q);
    __shared__ float rs[4], rq[4];
    if ((tid & 63) == 0) { rs[tid >> 6] = s; rq[tid >> 6] = q; }
    __syncthreads();
    if (tid == 0) {
        float S = rs[0] + rs[1] + rs[2] + rs[3];
        float Q = rq[0] + rq[1] + rq[2] + rq[3];
        float m = S * invN;
        float v = Q * invN - m * m;
        stats[c] = m; stats[C + c] = v;
    }
}

// conv1 pass 2 fused: recompute conv, BN inline, logits1, relu+pool -> x1
__global__ __launch_bounds__(256) void fused1_kernel(
        const float* __restrict__ inp, const float* __restrict__ w,
        const float* __restrict__ bias, const float* __restrict__ st,
        const float* __restrict__ g, const float* __restrict__ bb,
        const float* __restrict__ k1s, float* __restrict__ x1,
        float* __restrict__ outL1) {
    int b = blockIdx.x, tid = threadIdx.x;
    __shared__ float si[3072];      // input image  [3][32][32]
    __shared__ float sw[450];       // conv1 weights [6][75]
    __shared__ float act[4704];     // act1 [6][784]
    __shared__ float sk[384];       // k1s [64][6]
    __shared__ float sscale[6], sshift[6];
    for (int i = tid; i < 3072; i += 256) si[i] = inp[b * 3072 + i];
    for (int i = tid; i < 450; i += 256) sw[i] = w[i];
    for (int i = tid; i < 384; i += 256) sk[i] = k1s[i];
    if (tid < 6) {
        float m = st[tid], v = st[6 + tid];
        float sc = g[tid] / sqrtf(v + EPSV);
        sscale[tid] = sc;
        sshift[tid] = (bias[tid] - m) * sc + bb[tid];
    }
    __syncthreads();
    for (int i = tid; i < 4704; i += 256) {
        int c = i / 784, hw = i % 784;
        int oh = hw / 28, ow = hw % 28;
        float acc = 0.f;
#pragma unroll
        for (int ic = 0; ic < 3; ++ic) {
            const float* ip = si + ic * 1024 + oh * 32 + ow;
            const float* wp = sw + c * 75 + ic * 25;
#pragma unroll
            for (int kh = 0; kh < 5; ++kh)
#pragma unroll
                for (int kw = 0; kw < 5; ++kw)
                    acc += ip[kh * 32 + kw] * wp[kh * 5 + kw];
        }
        act[i] = acc * sscale[c] + sshift[c];
    }
    __syncthreads();
    float* op = outL1 + (long)b * 50176;
    for (int i = tid; i < 50176; i += 256) {
        int k = i / 784, hw = i % 784;
        float s = 0.f;
#pragma unroll
        for (int c = 0; c < 6; ++c) {
            float d = act[c * 784 + hw] - sk[k * 6 + c];
            s += d * d;
        }
        op[i] = -sqrtf(s);
    }
    for (int i = tid; i < 1176; i += 256) {
        int c = i / 196, p = i % 196, ph = p / 14, pw = p % 14;
        const float* ap = act + c * 784 + ph * 56 + pw * 2;
        float m = fmaxf(fmaxf(ap[0], ap[1]), fmaxf(ap[28], ap[29]));
        x1[b * 1176 + i] = fmaxf(m, 0.f);
    }
}

// conv2 pass 1: x1 [B,6,14,14] -> per-(b,c) partials only
__global__ void conv2_stats_kernel(const float* __restrict__ x1, const float* __restrict__ w,
                                   const float* __restrict__ bias, float* __restrict__ part) {
    int bc = blockIdx.x; int b = bc >> 4, c = bc & 15;
    int tid = threadIdx.x;  // 128
    __shared__ float xs[1176];
    __shared__ float ws[150];
    __shared__ float rs[2], rq[2];
    for (int i = tid; i < 1176; i += 128) xs[i] = x1[b * 1176 + i];
    for (int i = tid; i < 150; i += 128) ws[i] = w[c * 150 + i];
    __syncthreads();
    float val = 0.f;
    if (tid < 100) {
        int oh = tid / 10, ow = tid % 10;
        float acc = bias[c];
#pragma unroll
        for (int ic = 0; ic < 6; ++ic) {
            const float* xp = xs + ic * 196 + oh * 14 + ow;
            const float* wp = ws + ic * 25;
#pragma unroll
            for (int kh = 0; kh < 5; ++kh)
#pragma unroll
                for (int kw = 0; kw < 5; ++kw)
                    acc += xp[kh * 14 + kw] * wp[kh * 5 + kw];
        }
        val = acc;
    }
    float s = val, sq = val * val;
    wave_reduce2(s, sq);
    if ((tid & 63) == 0) { rs[tid >> 6] = s; rq[tid >> 6] = sq; }
    __syncthreads();
    if (tid == 0) {
        part[bc * 2]     = rs[0] + rs[1];
        part[bc * 2 + 1] = rq[0] + rq[1];
    }
}

// conv2 pass 2 fused: recompute conv, BN inline, logits2, relu+pool -> x2
__global__ __launch_bounds__(256) void fused2_kernel(
        const float* __restrict__ x1, const float* __restrict__ w,
        const float* __restrict__ bias, const float* __restrict__ st,
        const float* __restrict__ g, const float* __restrict__ bb,
        const float* __restrict__ k2s, float* __restrict__ x2,
        float* __restrict__ outL2) {
    int b = blockIdx.x, tid = threadIdx.x;
    __shared__ float xs[1176];     // x1[b] [6][196]
    __shared__ float sw[2400];     // conv2 weights [16][150]
    __shared__ float act[1600];    // act2 [16][100]
    __shared__ float sk[1024];     // k2s [64][16]
    __shared__ float sscale[16], sshift[16];
    for (int i = tid; i < 1176; i += 256) xs[i] = x1[b * 1176 + i];
    for (int i = tid; i < 2400; i += 256) sw[i] = w[i];
    for (int i = tid; i < 1024; i += 256) sk[i] = k2s[i];
    if (tid < 16) {
        float m = st[tid], v = st[16 + tid];
        float sc = g[tid] / sqrtf(v + EPSV);
        sscale[tid] = sc;
        sshift[tid] = (bias[tid] - m) * sc + bb[tid];
    }
    __syncthreads();
    for (int i = tid; i < 1600; i += 256) {
        int c = i / 100, hw = i % 100;
        int oh = hw / 10, ow = hw % 10;
        float acc = 0.f;
#pragma unroll
        for (int ic = 0; ic < 6; ++ic) {
            const float* xp = xs + ic * 196 + oh * 14 + ow;
            const float* wp = sw + c * 150 + ic * 25;
#pragma unroll
            for (int kh = 0; kh < 5; ++kh)
#pragma unroll
                for (int kw = 0; kw < 5; ++kw)
                    acc += xp[kh * 14 + kw] * wp[kh * 5 + kw];
        }
        act[i] = acc * sscale[c] + sshift[c];
    }
    __syncthreads();
    float* op = outL2 + (long)b * 6400;
    for (int i = tid; i < 6400; i += 256) {
        int k = i / 100, hw = i % 100;
        float s = 0.f;
#pragma unroll
        for (int c = 0; c < 16; ++c) {
            float d = act[c * 100 + hw] - sk[k * 16 + c];
            s += d * d;
        }
        op[i] = -sqrtf(s);
    }
    for (int i = tid; i < 400; i += 256) {
        int c = i / 25, p = i % 25, ph = p / 5, pw = p % 5;
        const float* ap = act + c * 100 + ph * 20 + pw * 2;
        float m = fmaxf(fmaxf(ap[0], ap[1]), fmaxf(ap[10], ap[11]));
        x2[b * 400 + i] = fmaxf(m, 0.f);
    }
}

// fc1 + relu + fc2; block per b
__global__ void fc_kernel(const float* __restrict__ x2, const float* __restrict__ w1,
                          const float* __restrict__ b1, const float* __restrict__ w2,
                          const float* __restrict__ b2, float* __restrict__ act3,
                          float* __restrict__ out_act4) {
    int b = blockIdx.x, tid = threadIdx.x;  // 128
    __shared__ float xs[400];
    __shared__ float a3[120];
    for (int i = tid; i < 400; i += 128) xs[i] = x2[b * 400 + i];
    __syncthreads();
    if (tid < 120) {
        float acc = b1[tid];
        for (int c = 0; c < 400; ++c) acc += xs[c] * w1[tid * 400 + c];
        act3[b * 120 + tid] = acc;
        a3[tid] = fmaxf(acc, 0.f);
    }
    __syncthreads();
    if (tid < 10) {
        float acc = b2[tid];
#pragma unroll
        for (int c = 0; c < 120; ++c) acc += a3[c] * w2[tid * 120 + c];
        out_act4[b * 10 + tid] = acc;
    }
}

// logits3: act3 [B,120], k3s [512,120] -> out f32 [B,512]
__global__ void logits3_kernel(const float* __restrict__ act3, const float* __restrict__ k3s,
                               float* __restrict__ out) {
    int b = blockIdx.x, k = threadIdx.x;  // 512
    __shared__ float a[120];
    if (k < 120) a[k] = act3[b * 120 + k];
    __syncthreads();
    float s = 0.f;
    for (int c = 0; c < 120; ++c) { float d = a[c] - k3s[k * 120 + c]; s += d * d; }
    out[b * 512 + k] = -sqrtf(s);
}

// neural-gas: argmax (first occurrence) + bitonic sort + weighted sumsq
__global__ void ng_kernel(const float* __restrict__ l3f, float* __restrict__ loss_b,
                          float* __restrict__ out_assign) {
    int b = blockIdx.x, tid = threadIdx.x;  // 512
    __shared__ float sv[512];
    __shared__ float rv[512];
    __shared__ int   ri[512];
    float v = l3f[b * 512 + tid];
    sv[tid] = v; rv[tid] = v; ri[tid] = tid;
    __syncthreads();
    for (int s = 256; s > 0; s >>= 1) {
        if (tid < s) {
            float ov = rv[tid + s]; int oi = ri[tid + s];
            if (ov > rv[tid] || (ov == rv[tid] && oi < ri[tid])) { rv[tid] = ov; ri[tid] = oi; }
        }
        __syncthreads();
    }
    if (tid == 0) out_assign[b] = (float)ri[0];
    for (int k = 2; k <= 512; k <<= 1) {
        for (int j = k >> 1; j > 0; j >>= 1) {
            int ixj = tid ^ j;
            if (ixj > tid) {
                bool up = ((tid & k) == 0);
                float x = sv[tid], y = sv[ixj];
                if ((x > y) == up) { sv[tid] = y; sv[ixj] = x; }
            }
            __syncthreads();
        }
    }
    float w = expf(-(float)tid);
    rv[tid] = sv[tid] * sv[tid] * w;
    __syncthreads();
    for (int s = 256; s > 0; s >>= 1) {
        if (tid < s) rv[tid] += rv[tid + s];
        __syncthreads();
    }
    if (tid == 0) loss_b[b] = rv[0];
}

__global__ void final_kernel(const float* __restrict__ loss_b, float* __restrict__ out_loss) {
    __shared__ float r[256];
    int tid = threadIdx.x;
    r[tid] = loss_b[tid];
    __syncthreads();
    for (int s = 128; s > 0; s >>= 1) {
        if (tid < s) r[tid] += r[tid + s];
        __syncthreads();
    }
    if (tid == 0) out_loss[0] = r[0] / 256.f;
}

extern "C" void kernel_launch(void* const* d_in, const int* in_sizes, int n_in,
                              void* d_out, int out_size, void* d_ws, size_t ws_size,
                              hipStream_t stream) {
    const float* inp = (const float*)d_in[0];
    const float* c1w = (const float*)d_in[1];
    const float* c1b = (const float*)d_in[2];
    const float* g1  = (const float*)d_in[3];
    const float* bb1 = (const float*)d_in[4];
    const float* c2w = (const float*)d_in[5];
    const float* c2b = (const float*)d_in[6];
    const float* g2  = (const float*)d_in[7];
    const float* bb2 = (const float*)d_in[8];
    const float* f1w = (const float*)d_in[9];
    const float* f1b = (const float*)d_in[10];
    const float* f2w = (const float*)d_in[11];
    const float* f2b = (const float*)d_in[12];
    const float* k1  = (const float*)d_in[13];
    const float* k2  = (const float*)d_in[14];
    const float* k3  = (const float*)d_in[15];
    float* out = (float*)d_out;

    // workspace layout (floats) — total ~446k floats = 1.8 MB
    float* W = (float*)d_ws;
    float* x1    = W;                  // 301056
    float* x2    = x1 + 301056;        // 102400
    float* act3  = x2 + 102400;        // 30720
    float* part1 = act3 + 30720;       // 3072
    float* part2 = part1 + 3072;       // 8192
    float* st1   = part2 + 8192;       // 12
    float* st2   = st1 + 12;           // 32
    float* lossb = st2 + 32;           // 256

    conv1_stats_kernel<<<B * 6, 256, 0, stream>>>(inp, c1w, c1b, part1);
    stats_kernel<<<6, 256, 0, stream>>>(part1, st1, 6, 1.f / 200704.f);
    fused1_kernel<<<B, 256, 0, stream>>>(inp, c1w, c1b, st1, g1, bb1, k1, x1, out + OFF_L1);
    conv2_stats_kernel<<<B * 16, 128, 0, stream>>>(x1, c2w, c2b, part2);
    stats_kernel<<<16, 256, 0, stream>>>(part2, st2, 16, 1.f / 25600.f);
    fused2_kernel<<<B, 256, 0, stream>>>(x1, c2w, c2b, st2, g2, bb2, k2, x2, out + OFF_L2);
    fc_kernel<<<B, 128, 0, stream>>>(x2, f1w, f1b, f2w, f2b, act3, out + OFF_ACT4);
    logits3_kernel<<<B, 512, 0, stream>>>(act3, k3, out + OFF_L3);
    ng_kernel<<<B, 512, 0, stream>>>(out + OFF_L3, lossb, out + OFF_ASSIGN);
    final_kernel<<<1, 256, 0, stream>>>(lossb, out + OFF_LOSS);
}

// Round 4
// 119.578 us; speedup vs baseline: 1.3303x; 1.3303x over previous
//
#include <hip/hip_runtime.h>

#define B 256
#define EPSV 1e-5f

// ---------- output offsets (f32 elements) ----------
#define OFF_ASSIGN 0
#define OFF_LOSS   256
#define OFF_ACT4   257
#define OFF_L1     2817
#define OFF_L2     12847873
#define OFF_L3     14486273

__device__ inline void wave_reduce2(float& s, float& q) {
#pragma unroll
    for (int o = 32; o > 0; o >>= 1) {
        s += __shfl_down(s, o, 64);
        q += __shfl_down(q, o, 64);
    }
}

// conv1: [B,3,32,32] -> raw c1 [B,6,28,28] + per-(b,c) sum/sumsq partials
__global__ __launch_bounds__(256) void conv1_kernel(
        const float* __restrict__ inp, const float* __restrict__ w,
        const float* __restrict__ bias, float* __restrict__ c1,
        float* __restrict__ part) {
    int bc = blockIdx.x; int b = bc / 6, c = bc % 6;
    int tid = threadIdx.x;
    __shared__ float ws[75];
    __shared__ float rs[4], rq[4];
    if (tid < 75) ws[tid] = w[c * 75 + tid];
    __syncthreads();
    const float* ip = inp + b * 3072;
    float bs = bias[c];
    float s = 0.f, sq = 0.f;
    for (int hw = tid; hw < 784; hw += 256) {
        int oh = hw / 28, ow = hw % 28;
        float acc = bs;
#pragma unroll
        for (int ic = 0; ic < 3; ++ic) {
            const float* ipc = ip + ic * 1024 + oh * 32 + ow;
            const float* wc = ws + ic * 25;
#pragma unroll
            for (int kh = 0; kh < 5; ++kh)
#pragma unroll
                for (int kw = 0; kw < 5; ++kw)
                    acc += ipc[kh * 32 + kw] * wc[kh * 5 + kw];
        }
        c1[bc * 784 + hw] = acc;
        s += acc; sq += acc * acc;
    }
    wave_reduce2(s, sq);
    if ((tid & 63) == 0) { rs[tid >> 6] = s; rq[tid >> 6] = sq; }
    __syncthreads();
    if (tid == 0) {
        part[bc * 2]     = rs[0] + rs[1] + rs[2] + rs[3];
        part[bc * 2 + 1] = rq[0] + rq[1] + rq[2] + rq[3];
    }
}

// per-channel stats from B partials; grid = C blocks, 256 thr (one per b)
__global__ void stats_kernel(const float* __restrict__ part, float* __restrict__ stats,
                             int C, float invN) {
    int c = blockIdx.x, tid = threadIdx.x;
    float s = part[(tid * C + c) * 2];
    float q = part[(tid * C + c) * 2 + 1];
    wave_reduce2(s, q);
    __shared__ float rs[4], rq[4];
    if ((tid & 63) == 0) { rs[tid >> 6] = s; rq[tid >> 6] = q; }
    __syncthreads();
    if (tid == 0) {
        float S = rs[0] + rs[1] + rs[2] + rs[3];
        float Q = rq[0] + rq[1] + rq[2] + rq[3];
        float m = S * invN;
        float v = Q * invN - m * m;
        stats[c] = m; stats[C + c] = v;
    }
}

// BN + relu + 2x2 pool: raw c1 -> x1 [B,6,14,14]; one thread per pooled elem
__global__ __launch_bounds__(256) void bnpool1_kernel(
        const float* __restrict__ c1, const float* __restrict__ st,
        const float* __restrict__ g, const float* __restrict__ bb,
        float* __restrict__ x1) {
    int i = blockIdx.x * 256 + threadIdx.x;  // 301056
    int pw = i % 14; int t = i / 14; int ph = t % 14; t /= 14; int c = t % 6; int b = t / 6;
    float m = st[c], v = st[6 + c];
    float sc = g[c] * rsqrtf(v + EPSV);
    float sh = bb[c] - m * sc;
    const float* ap = c1 + (b * 6 + c) * 784 + ph * 56 + pw * 2;
    float v0 = ap[0] * sc + sh, v1 = ap[1] * sc + sh;
    float v2 = ap[28] * sc + sh, v3 = ap[29] * sc + sh;
    x1[i] = fmaxf(fmaxf(fmaxf(v0, v1), fmaxf(v2, v3)), 0.f);
}

// logits1: raw c1 + BN inline, k1s [64,6] -> out [B,64,28,28]; 4 k's per thread
__global__ __launch_bounds__(256) void logits1_kernel(
        const float* __restrict__ c1, const float* __restrict__ st,
        const float* __restrict__ g, const float* __restrict__ bb,
        const float* __restrict__ k1s, float* __restrict__ outL1) {
    __shared__ float sk[384];
    __shared__ float ssc[6], ssh[6];
    int tid = threadIdx.x;
    if (tid < 6) {
        float m = st[tid], v = st[6 + tid];
        float sc = g[tid] * rsqrtf(v + EPSV);
        ssc[tid] = sc; ssh[tid] = bb[tid] - m * sc;
    }
    for (int i = tid; i < 384; i += 256) sk[i] = k1s[i];
    __syncthreads();
    int t = blockIdx.x * 256 + tid;          // B*16*784 = 3211264
    int hw = t % 784; int u = t / 784; int kq = u & 15; int b = u >> 4;
    float a[6];
#pragma unroll
    for (int c = 0; c < 6; ++c)
        a[c] = c1[(b * 6 + c) * 784 + hw] * ssc[c] + ssh[c];
    float* op = outL1 + (long)b * 50176 + kq * 3136 + hw;
#pragma unroll
    for (int j = 0; j < 4; ++j) {
        int k = kq * 4 + j;
        float s = 0.f;
#pragma unroll
        for (int c = 0; c < 6; ++c) { float d = a[c] - sk[k * 6 + c]; s += d * d; }
        op[j * 784] = -sqrtf(s);
    }
}

// conv2: x1 [B,6,14,14] -> raw c2 [B,16,10,10] + partials; block=(b,c), 128 thr
__global__ __launch_bounds__(128) void conv2_kernel(
        const float* __restrict__ x1, const float* __restrict__ w,
        const float* __restrict__ bias, float* __restrict__ c2,
        float* __restrict__ part) {
    int bc = blockIdx.x; int b = bc >> 4, c = bc & 15;
    int tid = threadIdx.x;  // 128
    __shared__ float xs[1176];
    __shared__ float ws[150];
    __shared__ float rs[2], rq[2];
    for (int i = tid; i < 1176; i += 128) xs[i] = x1[b * 1176 + i];
    for (int i = tid; i < 150; i += 128) ws[i] = w[c * 150 + i];
    __syncthreads();
    float val = 0.f;
    if (tid < 100) {
        int oh = tid / 10, ow = tid % 10;
        float acc = bias[c];
#pragma unroll
        for (int ic = 0; ic < 6; ++ic) {
            const float* xp = xs + ic * 196 + oh * 14 + ow;
            const float* wp = ws + ic * 25;
#pragma unroll
            for (int kh = 0; kh < 5; ++kh)
#pragma unroll
                for (int kw = 0; kw < 5; ++kw)
                    acc += xp[kh * 14 + kw] * wp[kh * 5 + kw];
        }
        c2[bc * 100 + tid] = acc;
        val = acc;
    }
    float s = val, sq = val * val;
    wave_reduce2(s, sq);
    if ((tid & 63) == 0) { rs[tid >> 6] = s; rq[tid >> 6] = sq; }
    __syncthreads();
    if (tid == 0) {
        part[bc * 2]     = rs[0] + rs[1];
        part[bc * 2 + 1] = rq[0] + rq[1];
    }
}

// BN + relu + 2x2 pool: raw c2 -> x2 [B,16,5,5]
__global__ __launch_bounds__(256) void bnpool2_kernel(
        const float* __restrict__ c2, const float* __restrict__ st,
        const float* __restrict__ g, const float* __restrict__ bb,
        float* __restrict__ x2) {
    int i = blockIdx.x * 256 + threadIdx.x;  // 102400
    int pw = i % 5; int t = i / 5; int ph = t % 5; t /= 5; int c = t % 16; int b = t / 16;
    float m = st[c], v = st[16 + c];
    float sc = g[c] * rsqrtf(v + EPSV);
    float sh = bb[c] - m * sc;
    const float* ap = c2 + (b * 16 + c) * 100 + ph * 20 + pw * 2;
    float v0 = ap[0] * sc + sh, v1 = ap[1] * sc + sh;
    float v2 = ap[10] * sc + sh, v3 = ap[11] * sc + sh;
    x2[i] = fmaxf(fmaxf(fmaxf(v0, v1), fmaxf(v2, v3)), 0.f);
}

// logits2: raw c2 + BN inline (act2 staged in LDS), k2s [64,16] -> out [B,64,10,10]
__global__ __launch_bounds__(256) void logits2_kernel(
        const float* __restrict__ c2, const float* __restrict__ st,
        const float* __restrict__ g, const float* __restrict__ bb,
        const float* __restrict__ k2s, float* __restrict__ outL2) {
    __shared__ float sk[1024];
    __shared__ float sa[1600];
    __shared__ float ssc[16], ssh[16];
    int tid = threadIdx.x;
    int t0 = blockIdx.x * 256;
    int b = t0 / 6400;                       // constant per block (6400 % 256 == 0)
    if (tid < 16) {
        float m = st[tid], v = st[16 + tid];
        float sc = g[tid] * rsqrtf(v + EPSV);
        ssc[tid] = sc; ssh[tid] = bb[tid] - m * sc;
    }
    for (int i = tid; i < 1024; i += 256) sk[i] = k2s[i];
    __syncthreads();
    for (int i = tid; i < 1600; i += 256) {
        int c = i / 100;
        sa[i] = c2[b * 1600 + i] * ssc[c] + ssh[c];
    }
    __syncthreads();
    int t = t0 + tid;
    int hw = t % 100; int k = (t / 100) & 63;
    float s = 0.f;
#pragma unroll
    for (int c = 0; c < 16; ++c) { float d = sa[c * 100 + hw] - sk[k * 16 + c]; s += d * d; }
    outL2[t] = -sqrtf(s);
}

// head: fc1 + act4 + logits3 + argmax + bitonic sort + NG weighted loss; block per b, 512 thr
__global__ __launch_bounds__(512) void head_kernel(
        const float* __restrict__ x2, const float* __restrict__ w1,
        const float* __restrict__ b1, const float* __restrict__ w2,
        const float* __restrict__ b2, const float* __restrict__ k3s,
        float* __restrict__ outAct4, float* __restrict__ outL3,
        float* __restrict__ outAssign, float* __restrict__ lossb) {
    int b = blockIdx.x, tid = threadIdx.x;
    __shared__ float xs[400];
    __shared__ float a3r[120], a3p[120];
    __shared__ float sv[512], rv[512];
    __shared__ int ri[512];
    for (int i = tid; i < 400; i += 512) xs[i] = x2[b * 400 + i];
    __syncthreads();
    if (tid < 480) {                          // fc1: 120 dots, 4-way split + shfl combine
        int o = tid >> 2, q = tid & 3;
        const float* wp = w1 + o * 400 + q * 100;
        const float* xp = xs + q * 100;
        float s = 0.f;
#pragma unroll 4
        for (int c = 0; c < 100; ++c) s += xp[c] * wp[c];
        s += __shfl_down(s, 2, 64);
        s += __shfl_down(s, 1, 64);
        if (q == 0) {
            float acc = s + b1[o];
            a3r[o] = acc;
            a3p[o] = fmaxf(acc, 0.f);
        }
    }
    __syncthreads();
    {   // logits3 (from RAW act3, pre-relu)
        const float* kp = k3s + tid * 120;
        float s = 0.f;
        for (int c = 0; c < 120; ++c) { float d = a3r[c] - kp[c]; s += d * d; }
        float v = -sqrtf(s);
        sv[tid] = v; rv[tid] = v; ri[tid] = tid;
        outL3[b * 512 + tid] = v;
    }
    if (tid < 10) {                           // fc2 from relu(act3)
        float acc = b2[tid];
        const float* wp = w2 + tid * 120;
#pragma unroll 4
        for (int c = 0; c < 120; ++c) acc += a3p[c] * wp[c];
        outAct4[b * 10 + tid] = acc;
    }
    __syncthreads();
    for (int s = 256; s > 0; s >>= 1) {       // argmax, first occurrence
        if (tid < s) {
            float ov = rv[tid + s]; int oi = ri[tid + s];
            if (ov > rv[tid] || (ov == rv[tid] && oi < ri[tid])) { rv[tid] = ov; ri[tid] = oi; }
        }
        __syncthreads();
    }
    if (tid == 0) outAssign[b] = (float)ri[0];
    for (int k = 2; k <= 512; k <<= 1)        // bitonic sort ascending
        for (int j = k >> 1; j > 0; j >>= 1) {
            int ixj = tid ^ j;
            if (ixj > tid) {
                bool up = ((tid & k) == 0);
                float x = sv[tid], y = sv[ixj];
                if ((x > y) == up) { sv[tid] = y; sv[ixj] = x; }
            }
            __syncthreads();
        }
    float wgt = expf(-(float)tid);
    rv[tid] = sv[tid] * sv[tid] * wgt;
    __syncthreads();
    for (int s = 256; s > 0; s >>= 1) {
        if (tid < s) rv[tid] += rv[tid + s];
        __syncthreads();
    }
    if (tid == 0) lossb[b] = rv[0];
}

__global__ void final_kernel(const float* __restrict__ loss_b, float* __restrict__ out_loss) {
    __shared__ float r[256];
    int tid = threadIdx.x;
    r[tid] = loss_b[tid];
    __syncthreads();
    for (int s = 128; s > 0; s >>= 1) {
        if (tid < s) r[tid] += r[tid + s];
        __syncthreads();
    }
    if (tid == 0) out_loss[0] = r[0] / 256.f;
}

extern "C" void kernel_launch(void* const* d_in, const int* in_sizes, int n_in,
                              void* d_out, int out_size, void* d_ws, size_t ws_size,
                              hipStream_t stream) {
    const float* inp = (const float*)d_in[0];
    const float* c1w = (const float*)d_in[1];
    const float* c1b = (const float*)d_in[2];
    const float* g1  = (const float*)d_in[3];
    const float* bb1 = (const float*)d_in[4];
    const float* c2w = (const float*)d_in[5];
    const float* c2b = (const float*)d_in[6];
    const float* g2  = (const float*)d_in[7];
    const float* bb2 = (const float*)d_in[8];
    const float* f1w = (const float*)d_in[9];
    const float* f1b = (const float*)d_in[10];
    const float* f2w = (const float*)d_in[11];
    const float* f2b = (const float*)d_in[12];
    const float* k1  = (const float*)d_in[13];
    const float* k2  = (const float*)d_in[14];
    const float* k3  = (const float*)d_in[15];
    float* out = (float*)d_out;

    // Stash raw c1 (1204224 f) and x1 (301056 f) in the logits2 output region
    // (1638400 f) — it is only written later in stream order, and logits2
    // fully overwrites it before validation.
    float* c1raw = out + OFF_L2;               // 1204224
    float* x1    = c1raw + 1204224;            // 301056 (ends at 1505280 < 1638400)

    // workspace layout (floats) — ~523k floats = 2.09 MB
    float* W = (float*)d_ws;
    float* c2raw = W;                  // 409600
    float* x2    = c2raw + 409600;     // 102400
    float* part1 = x2 + 102400;        // 3072
    float* part2 = part1 + 3072;       // 8192
    float* st1   = part2 + 8192;       // 12
    float* st2   = st1 + 12;           // 32
    float* lossb = st2 + 32;           // 256

    conv1_kernel<<<B * 6, 256, 0, stream>>>(inp, c1w, c1b, c1raw, part1);
    stats_kernel<<<6, 256, 0, stream>>>(part1, st1, 6, 1.f / 200704.f);
    bnpool1_kernel<<<1176, 256, 0, stream>>>(c1raw, st1, g1, bb1, x1);
    logits1_kernel<<<12544, 256, 0, stream>>>(c1raw, st1, g1, bb1, k1, out + OFF_L1);
    conv2_kernel<<<B * 16, 128, 0, stream>>>(x1, c2w, c2b, c2raw, part2);
    stats_kernel<<<16, 256, 0, stream>>>(part2, st2, 16, 1.f / 25600.f);
    bnpool2_kernel<<<400, 256, 0, stream>>>(c2raw, st2, g2, bb2, x2);
    logits2_kernel<<<6400, 256, 0, stream>>>(c2raw, st2, g2, bb2, k2, out + OFF_L2);
    head_kernel<<<B, 512, 0, stream>>>(x2, f1w, f1b, f2w, f2b, k3,
                                       out + OFF_ACT4, out + OFF_L3, out + OFF_ASSIGN, lossb);
    final_kernel<<<1, 256, 0, stream>>>(lossb, out + OFF_LOSS);
}